// Round 3
// baseline (201.276 us; speedup 1.0000x reference)
//
#include <hip/hip_runtime.h>

// AssistedExcitation: out = x * (1 + ALPHA * att(b,h,w))
// att = 5x5-gaussian-smoothed union mask of 32 boxes, per batch.
// x: [16,256,80,80] fp32, boxes: [16,32,4] fp32, kernel: [1,1,5,5] fp32.

namespace {
constexpr int kB = 16;
constexpr int kC = 256;
constexpr int kH = 80;
constexpr int kW = 80;
constexpr int kNBox = 32;
constexpr float kAlpha = 1.0f;

__device__ __forceinline__ int reflect_idx(int r, int n) {
    // jnp.pad mode='reflect': -1 -> 1, -2 -> 2 ; n -> n-2, n+1 -> n-3
    return r < 0 ? -r : (r > n - 1 ? 2 * (n - 1) - r : r);
}
}  // namespace

// grid = kB*kH blocks (one per output row), 320 threads (= 16 channels x 20 float4)
__global__ __launch_bounds__(320) void ae_fused_kernel(
    const float* __restrict__ x,
    const float* __restrict__ boxes,
    const float* __restrict__ gk,
    float* __restrict__ out)
{
    __shared__ int sx1[kNBox], sy1[kNBox], sx2[kNBox], sy2[kNBox];
    __shared__ float sk[25];
    __shared__ float smask[5][kW];
    __shared__ __attribute__((aligned(16))) float sfac[kW];  // 1 + alpha*att

    const int b = blockIdx.x / kH;
    const int h = blockIdx.x % kH;
    const int t = threadIdx.x;

    // ---- phase 1: box rects (match reference trunc/clamp semantics) ----
    if (t < kNBox) {
        const float* bp = boxes + (size_t)(b * kNBox + t) * 4;
        float xc = bp[0], yc = bp[1], bw = bp[2], bh = bp[3];
        float fx1 = fmaxf(0.0f, truncf((xc - bw * 0.5f) * (float)kW));
        float fy1 = fmaxf(0.0f, truncf((yc - bh * 0.5f) * (float)kH));
        float fx2 = fminf((float)(kW - 1), truncf((xc + bw * 0.5f) * (float)kW));
        float fy2 = fminf((float)(kH - 1), truncf((yc + bh * 0.5f) * (float)kH));
        int ix1 = (int)fx1, iy1 = (int)fy1, ix2 = (int)fx2, iy2 = (int)fy2;
        bool valid = (ix2 > ix1) && (iy2 > iy1);
        sx1[t] = ix1;
        sx2[t] = ix2;
        sy1[t] = valid ? iy1 : 1;   // empty range when invalid
        sy2[t] = valid ? iy2 : 0;
    } else if (t >= 64 && t < 64 + 25) {
        sk[t - 64] = gk[t - 64];
    }
    __syncthreads();

    // ---- phase 2: rasterize the 5 reflected mask rows needed by this h ----
    for (int p = t; p < 5 * kW; p += 320) {
        int i = p / kW, c = p % kW;
        int rr = reflect_idx(h + i - 2, kH);
        float m = 0.0f;
#pragma unroll
        for (int n = 0; n < kNBox; ++n) {
            bool in = (rr >= sy1[n]) && (rr <= sy2[n]) && (c >= sx1[n]) && (c <= sx2[n]);
            m = in ? 1.0f : m;
        }
        smask[i][c] = m;
    }
    __syncthreads();

    // ---- phase 3: 25-tap conv with reflected cols -> per-w scale factor ----
    if (t < kW) {
        float acc = 0.0f;
#pragma unroll
        for (int i = 0; i < 5; ++i) {
#pragma unroll
            for (int j = 0; j < 5; ++j) {
                int cc = reflect_idx(t + j - 2, kW);
                acc += sk[i * 5 + j] * smask[i][cc];
            }
        }
        sfac[t] = 1.0f + kAlpha * acc;
    }
    __syncthreads();

    // ---- phase 4: stream 256 channels of this row, float4-coalesced ----
    const int j = t % 20;       // float4 index within the 80-wide row
    const int c0 = t / 20;      // 0..15
    const float4 f4 = *reinterpret_cast<const float4*>(&sfac[j * 4]);
    const size_t rowbase = (size_t)b * (kC * kH * kW / 4) + (size_t)h * (kW / 4);
    const float4* x4 = reinterpret_cast<const float4*>(x) + rowbase;
    float4* o4 = reinterpret_cast<float4*>(out) + rowbase;
#pragma unroll
    for (int it = 0; it < kC / 16; ++it) {
        int c = c0 + it * 16;
        size_t off = (size_t)c * (kH * kW / 4) + j;
        float4 v = x4[off];
        v.x *= f4.x;
        v.y *= f4.y;
        v.z *= f4.z;
        v.w *= f4.w;
        o4[off] = v;
    }
}

extern "C" void kernel_launch(void* const* d_in, const int* in_sizes, int n_in,
                              void* d_out, int out_size, void* d_ws, size_t ws_size,
                              hipStream_t stream) {
    const float* x     = (const float*)d_in[0];
    const float* boxes = (const float*)d_in[1];
    const float* gk    = (const float*)d_in[2];
    float* out         = (float*)d_out;

    dim3 grid(kB * kH);
    dim3 block(320);
    ae_fused_kernel<<<grid, block, 0, stream>>>(x, boxes, gk, out);
}